// Round 18
// baseline (210.605 us; speedup 1.0000x reference)
//
#include <hip/hip_runtime.h>
#include <hip/hip_bf16.h>

constexpr int BATCH = 4;
constexpr int H = 96, W = 96, HW = H * W;
constexpr int NBR = 3;

using bf16x8 = __attribute__((ext_vector_type(8))) short;  // 8 bf16 in 4 VGPRs
using f32x4 = __attribute__((ext_vector_type(4))) float;

static __device__ __forceinline__ float leakyf(float x) {
    return x >= 0.f ? x : 0.1f * x;
}

static __device__ __forceinline__ short f2bf(float x) {
    __hip_bfloat16 h = __float2bfloat16(x);
    return *reinterpret_cast<short*>(&h);
}

static __device__ __forceinline__ float bf2f(short s) {
    __hip_bfloat16 h = *reinterpret_cast<__hip_bfloat16*>(&s);
    return __bfloat162float(h);
}

// ---- fused: ref NCHW fp32 -> REFT (bf16 ch-last) + NRT (normalized ch-last)
__global__ __launch_bounds__(256) void k_pre(const float* __restrict__ ref,
                                             short* __restrict__ reft,
                                             float* __restrict__ nrt) {
    int p = blockIdx.x * 256 + threadIdx.x;
    if (p >= BATCH * HW) return;
    int b = p / HW, ij = p % HW;
    const float* src = ref + b * 64 * HW + ij;
    float v[64];
    float ss = 0.f;
#pragma unroll
    for (int c = 0; c < 64; ++c) {
        v[c] = src[c * HW];
        ss += v[c] * v[c];
    }
    float inv = 1.f / fmaxf(sqrtf(ss), 1e-12f);
    short* rd = reft + (size_t)p * 64;
#pragma unroll
    for (int cc = 0; cc < 8; ++cc) {
        bf16x8 o;
#pragma unroll
        for (int j = 0; j < 8; ++j) o[j] = f2bf(v[cc * 8 + j]);
        *(bf16x8*)(rd + cc * 8) = o;
    }
    float* nd = nrt + (size_t)p * 64;
#pragma unroll
    for (int c = 0; c < 64; ++c) nd[c] = v[c] * inv;
}

// ---- conv-weight pack helper (OIHW fp32 -> MFMA-B fragments) ---------------
static __device__ __forceinline__ void packw(const float* __restrict__ src,
                                             short* __restrict__ dst, int i,
                                             int OC, int ICt, int ICsrc, int KH,
                                             int KW, int NT, int fold) {
    int e = i & 7, l = (i >> 3) & 63;
    int rest = i >> 9;
    int nt = rest % NT;
    rest /= NT;
    int ICK = ICt >> 5;
    int kk = rest % ICK;
    int tap = rest / ICK;
    int ic = kk * 32 + (l >> 4) * 8 + e;
    int oc = nt * 16 + (l & 15);
    int u = tap / KW, v = tap % KW;
    float val = 0.f;
    if (oc < OC) {
        val = src[((oc * ICsrc + ic) * KH + u) * KW + v];
        if (fold) val += src[((oc * ICsrc + 64 + ic) * KH + u) * KW + v];
    }
    dst[i] = f2bf(val);
}

// ---- ALL weight prep in one kernel: 6 conv packs + wnn B2 pack + zpad ------
constexpr int E1 = 36864, E2 = 36864, E3 = 28672, E4 = 28672, E5 = 46080,
              E6 = 73728, E7 = 110592;
constexpr int C1 = E1, C2 = C1 + E2, C3 = C2 + E3, C4 = C3 + E4, C5 = C4 + E5,
              C6 = C5 + E6, C7 = C6 + E7, CT = C7 + 8;
__global__ void k_prep_all(const float* __restrict__ w1,
                           const float* __restrict__ w2,
                           const float* __restrict__ w3,
                           const float* __restrict__ w4,
                           const float* __restrict__ wm,
                           const float* __restrict__ wf,
                           const float* __restrict__ wnn,
                           short* __restrict__ P1, short* __restrict__ P2,
                           short* __restrict__ P3, short* __restrict__ P4,
                           short* __restrict__ PM, short* __restrict__ PF,
                           short* __restrict__ B2, short* __restrict__ zpad) {
    int i = blockIdx.x * 256 + threadIdx.x;
    if (i >= CT) return;
    if (i < C1) {
        packw(w1, P1, i, 64, 64, 128, 3, 3, 4, 1);
    } else if (i < C2) {
        packw(w2, P2, i - C1, 64, 64, 64, 3, 3, 4, 0);
    } else if (i < C3) {
        packw(w3, P3, i - C2, 64, 64, 64, 7, 1, 4, 0);
    } else if (i < C4) {
        packw(w4, P4, i - C3, 64, 64, 64, 1, 7, 4, 0);
    } else if (i < C5) {
        packw(wm, PM, i - C4, 72, 64, 64, 3, 3, 5, 0);
    } else if (i < C6) {
        packw(wf, PF, i - C5, 64, 128, 128, 3, 3, 4, 0);
    } else if (i < C7) {
        int j = i - C6;
        int e = j & 7, l = (j >> 3) & 63;
        int t = (j >> 9) % 9;
        int h2 = (j / (512 * 9)) % 2;
        int n = (j / (512 * 9 * 2)) % 3;
        int nt = j / (512 * 9 * 2 * 3);
        int oc = nt * 16 + (l & 15);
        int c = h2 * 32 + (l >> 4) * 8 + e;
        int u = t / 3, v = t % 3;
        B2[j] = f2bf(wnn[((oc * 192 + n * 64 + c) * 3 + u) * 3 + v]);
    } else {
        zpad[i - C7] = 0;
    }
}

// ---- zero-fill of d>24 cells the mirror can never write (S borders) --------
__global__ void k_zfill(float* __restrict__ S) {
    int idx = blockIdx.x * 256 + threadIdx.x;
    if (idx >= BATCH * 24 * 98 * 49) return;
    int xp = idx % 49, x0 = xp * 2, x1 = x0 + 1;
    int y = (idx / 49) % 98;
    int dd = (idx / (49 * 98)) % 24;
    int b = idx / (49 * 98 * 24);
    int d = 25 + dd;
    int dy = d / 7, dx = d % 7;
    float* row = S + ((size_t)(b * 49 + d)) * (98 * 98) + y * 98;
    int yy = y + dy - 3;
    if (yy < 0 || yy >= 98) {
        row[x0] = 0.f;
        row[x1] = 0.f;
    } else {
        if (x0 + dx - 3 < 0 || x0 + dx - 3 >= 98) row[x0] = 0.f;
        if (x1 + dx - 3 < 0 || x1 + dx - 3 >= 98) row[x1] = 0.f;
    }
}

// ---- LDS-tiled correlation body: block = (batch, row-pair), acc[25]/thread -
constexpr int CORR_NCOL = 104;
constexpr int CORR_BYTES = (2 * 5 * CORR_NCOL + 2 * 2 * CORR_NCOL) * 16;  // 23296
static __device__ void corr_tile_body(const float* __restrict__ nrt,
                                      float* __restrict__ S, char* pool,
                                      int blk) {
    float4* f2s = (float4*)pool;                 // [g2][r5][NCOL]
    float4* f1s = f2s + 2 * 5 * CORR_NCOL;       // [g2][r2][NCOL]
    const int b = blk / 49;
    const int y0 = (blk % 49) * 2;
    const int tid = threadIdx.x;
    const int x = tid % 98, yloc = tid / 98;  // valid when tid < 196
    const int y = y0 + yloc;
    float acc[25];
#pragma unroll
    for (int d = 0; d < 25; ++d) acc[d] = 0.f;
    for (int c0 = 0; c0 < 64; c0 += 8) {
        for (int e = tid; e < 2 * 5 * CORR_NCOL; e += 256) {
            int sc = e % CORR_NCOL;
            int r = (e / CORR_NCOL) % 5;
            int g = e / (CORR_NCOL * 5);
            int iy = y0 - 4 + r, ix = sc - 4;
            float4 v = make_float4(0.f, 0.f, 0.f, 0.f);
            if (iy >= 0 && iy < H && ix >= 0 && ix < W)
                v = *(const float4*)(nrt + ((size_t)(b * HW) + iy * W + ix) * 64 +
                                     c0 + g * 4);
            f2s[(g * 5 + r) * CORR_NCOL + sc] = v;
        }
        for (int e = tid; e < 2 * 2 * CORR_NCOL; e += 256) {
            int sc = e % CORR_NCOL;
            int r = (e / CORR_NCOL) % 2;
            int g = e / (CORR_NCOL * 2);
            int iy = y0 - 1 + r, ix = sc - 4;
            float4 v = make_float4(0.f, 0.f, 0.f, 0.f);
            if (iy >= 0 && iy < H && ix >= 0 && ix < W)
                v = *(const float4*)(nrt + ((size_t)(b * HW) + iy * W + ix) * 64 +
                                     c0 + g * 4);
            f1s[(g * 2 + r) * CORR_NCOL + sc] = v;
        }
        __syncthreads();
        if (tid < 196) {
#pragma unroll
            for (int g = 0; g < 2; ++g) {
                float4 a = f1s[(g * 2 + yloc) * CORR_NCOL + (x + 3)];
#pragma unroll
                for (int d = 0; d < 25; ++d) {
                    const int dy = d / 7, dx = d % 7;
                    float4 q = f2s[(g * 5 + yloc + dy) * CORR_NCOL + (x + dx)];
                    acc[d] = fmaf(a.x, q.x,
                                  fmaf(a.y, q.y,
                                       fmaf(a.z, q.z, fmaf(a.w, q.w, acc[d]))));
                }
            }
        }
        __syncthreads();
    }
    if (tid < 196) {
#pragma unroll
        for (int d = 0; d < 25; ++d)
            S[((size_t)(b * 49 + d)) * (98 * 98) + y * 98 + x] = acc[d];
#pragma unroll
        for (int d = 0; d < 24; ++d) {
            const int dy = d / 7, dx = d % 7;
            int y2 = y + dy - 3, x2 = x + dx - 3;
            if (y2 >= 0 && y2 < 98 && x2 >= 0 && x2 < 98)
                S[((size_t)(b * 49 + 48 - d)) * (98 * 98) + y2 * 98 + x2] = acc[d];
        }
    }
}

// ---- topk tail body: 3x3 window-sum + top-3 (stable: strict >) -------------
static __device__ void topk_body(const float* __restrict__ S,
                                 int* __restrict__ idx3, int blk) {
    int p = blk * 256 + threadIdx.x;
    if (p >= BATCH * HW) return;
    int b = p / HW, i = (p % HW) / W, j = p % W;
    float v0 = -1e30f, v1 = -1e30f, v2 = -1e30f;
    int d0 = 0, d1 = 0, d2 = 0;
    for (int d = 0; d < 49; ++d) {
        const float* s = S + ((b * 49 + d) * 98 + i) * 98 + j;
        float v = 0.f;
#pragma unroll
        for (int u = 0; u < 3; ++u)
#pragma unroll
            for (int vv = 0; vv < 3; ++vv) v += s[u * 98 + vv];
        if (v > v0) {
            v2 = v1; d2 = d1; v1 = v0; d1 = d0; v0 = v; d0 = d;
        } else if (v > v1) {
            v2 = v1; d2 = d1; v1 = v; d1 = d;
        } else if (v > v2) {
            v2 = v; d2 = d;
        }
    }
    idx3[p * 3 + 0] = d0;
    idx3[p * 3 + 1] = d1;
    idx3[p * 3 + 2] = d2;
}

// ---- channel-last bf16 implicit-GEMM conv (fat: optional fused tail) -------
template <int KH, int KW, int IC, int OC, int OMODE, bool BLDS, int NSPL, int TAIL>
__global__ __launch_bounds__(256) void k_cmfma(
    const short* __restrict__ inA, const short* __restrict__ inB,
    const short* __restrict__ Bp, const float* __restrict__ bias,
    void* __restrict__ outp, const float* __restrict__ taux,
    float* __restrict__ tS, int* __restrict__ tidx, int convblks) {
    constexpr int TI = 8, TJ = 16;
    constexpr int PH = (KH - 1) / 2, PW = (KW - 1) / 2;
    constexpr int LR = TI + KH - 1, LC = TJ + KW - 1;
    constexpr int ICB = IC * 2;
    constexpr int LS = (ICB == 128) ? 7 : 8;
    constexpr int ICK = IC / 32;
    constexpr int NTF = (OC + 15) / 16;
    constexpr int NTb = NTF / NSPL;
    constexpr int TAPS = KH * KW;
    constexpr int NOCT = ICB / 16;
    constexpr int XS_BYTES = LR * LC * ICB;
    constexpr int BS_BYTES = BLDS ? TAPS * ICK * NTb * 1024 : 16;
    constexpr int CONV_BYTES = XS_BYTES + BS_BYTES;
    constexpr int POOL =
        (TAIL == 1 && CORR_BYTES > CONV_BYTES) ? CORR_BYTES : CONV_BYTES;
    __shared__ __align__(16) char pool[POOL];
    if (TAIL != 0 && (int)blockIdx.x >= convblks) {
        int xb = (int)blockIdx.x - convblks;
        if (TAIL == 1)
            corr_tile_body(taux, tS, pool, xb);
        else
            topk_body(taux, tidx, xb);
        return;
    }
    char* Xs = pool;
    short* Bs = (short*)(pool + XS_BYTES);
    const int lid = blockIdx.x;
    const int tj0 = (lid % 6) * TJ, ti0 = ((lid / 6) % 12) * TI;
    const int zz = lid / 72;
    const int b = zz / NSPL;
    const int nt0 = (zz % NSPL) * NTb;
    const int tid = threadIdx.x;
    if (BLDS) {
        for (int u2 = tid; u2 < TAPS * ICK * NTb * 64; u2 += 256) {
            int l2 = u2 & 63;
            int rest = u2 >> 6;
            int nt = rest % NTb;
            int qk = rest / NTb;
            ((bf16x8*)Bs)[u2] = ((const bf16x8*)Bp)[(qk * NTF + nt0 + nt) * 64 + l2];
        }
    }
    for (int u2 = tid; u2 < LR * LC * NOCT; u2 += 256) {
        int oct = u2 % NOCT;
        int hp = u2 / NOCT;
        int hr = hp / LC, hc = hp % LC;
        int gi = ti0 + hr - PH, gj = tj0 + hc - PW;
        bf16x8 v = {};
        if (gi >= 0 && gi < H && gj >= 0 && gj < W) {
            const short* s = (oct < 8) ? inA : inB;
            v = *(const bf16x8*)(s + (size_t)(b * HW + gi * W + gj) * 64 +
                                 (oct & 7) * 8);
        }
        int byte = hp * ICB + oct * 16;
        byte ^= ((byte >> LS) & 7) << 4;
        *(bf16x8*)(Xs + byte) = v;
    }
    __syncthreads();
    const int wave = tid >> 6, l = tid & 63;
    const int r = l & 15, q = l >> 4;
    const int mt0 = wave * 2;
    int p0 = mt0 * 16 + r, p1 = p0 + 16;
    int li0 = p0 >> 4, lj0 = p0 & 15, li1 = p1 >> 4, lj1 = p1 & 15;
    f32x4 acc[2][NTb] = {};
#pragma unroll
    for (int t = 0; t < TAPS; ++t) {
        const int u = t / KW, v = t % KW;
        int hp0 = (li0 + u) * LC + (lj0 + v);
        int hp1 = (li1 + u) * LC + (lj1 + v);
#pragma unroll
        for (int kk = 0; kk < ICK; ++kk) {
            int ab0 = hp0 * ICB + kk * 64 + q * 16;
            ab0 ^= ((ab0 >> LS) & 7) << 4;
            int ab1 = hp1 * ICB + kk * 64 + q * 16;
            ab1 ^= ((ab1 >> LS) & 7) << 4;
            bf16x8 a0 = *(const bf16x8*)(Xs + ab0);
            bf16x8 a1 = *(const bf16x8*)(Xs + ab1);
            const short* bbase =
                BLDS ? (const short*)Bs + (t * ICK + kk) * NTb * 512 + l * 8
                     : Bp + ((t * ICK + kk) * NTF + nt0) * 512 + l * 8;
#pragma unroll
            for (int nt = 0; nt < NTb; ++nt) {
                bf16x8 bv = *(const bf16x8*)(bbase + nt * 512);
                acc[0][nt] =
                    __builtin_amdgcn_mfma_f32_16x16x32_bf16(a0, bv, acc[0][nt], 0, 0, 0);
                acc[1][nt] =
                    __builtin_amdgcn_mfma_f32_16x16x32_bf16(a1, bv, acc[1][nt], 0, 0, 0);
            }
        }
    }
    const int col = l & 15;
#pragma unroll
    for (int mt = 0; mt < 2; ++mt)
#pragma unroll
        for (int nt = 0; nt < NTb; ++nt) {
            int oc = (nt0 + nt) * 16 + col;
            float bs = (oc < OC) ? bias[oc] : 0.f;
#pragma unroll
            for (int j = 0; j < 4; ++j) {
                int p = (mt0 + mt) * 16 + q * 4 + j;
                int gi = ti0 + (p >> 4), gj = tj0 + (p & 15);
                float val = acc[mt][nt][j] + bs;
                if (OMODE == 0) {
                    val = leakyf(val);
                    *((short*)outp + (size_t)(b * HW + gi * W + gj) * 64 + oc) =
                        f2bf(val);
                } else if (OMODE == 1) {
                    if (oc < 72)
                        *((short*)outp + (size_t)(b * HW + gi * W + gj) * 72 + oc) =
                            f2bf(val);
                } else {
                    val = leakyf(val);
                    *((float*)outp + (size_t)(b * 64 + oc) * HW + gi * W + gj) = val;
                }
            }
        }
}

// ---- MFMA gather-conv + mask reduce: NO LDS, NO BARRIERS -------------------
// A-fragments loaded directly from channel-last REFT into VGPRs (lane l:
// pixel l&15, channel octet (l>>4)*8 + h2*32 of the gathered location).
// 256 threads = 4 waves (one oc-slice each), PX=16 pixels/block, pure
// dataflow: the only sync is implicit waitcnt. B2/mask from L2.
__global__ __launch_bounds__(256) void k_agg_mfma(
    const short* __restrict__ refT, const int* __restrict__ idx3,
    const short* __restrict__ B2, const float* __restrict__ bnn,
    const short* __restrict__ maskT, const short* __restrict__ zpad,
    short* __restrict__ agg) {
    constexpr int PX = 16;
    const int bid = blockIdx.x;
    const int swz = (bid & 7) * ((int)gridDim.x >> 3) + (bid >> 3);
    const int p0 = swz * PX;  // 16-aligned, same row, same batch
    const int b = p0 / HW;
    const int i0 = (p0 % HW) / W;
    const int j0 = p0 % W;
    const int tid = threadIdx.x;
    const int wave = tid >> 6;  // oc slice
    const int lane = tid & 63;
    const int pxl = lane & 15;  // A-row pixel
    const int q = lane >> 4;    // k-octet
    int ib[NBR], jb[NBR];
#pragma unroll
    for (int n = 0; n < NBR; ++n) {
        int d = idx3[(p0 + pxl) * NBR + n];
        ib[n] = i0 + d / 7 - 4;
        jb[n] = j0 + pxl + d % 7 - 4;
    }
    f32x4 acc[9] = {};
    const short* Bw = B2 + (size_t)wave * (3 * 2 * 9 * 512) + lane * 8;
    for (int n = 0; n < NBR; ++n) {
        const short* abase =
            refT + ((size_t)(b * HW) + ib[n] * W + jb[n]) * 64 + q * 8;
        bool ok[9];
#pragma unroll
        for (int rs = 0; rs < 9; ++rs) {
            int gi = ib[n] + rs / 3, gj = jb[n] + rs % 3;
            ok[rs] = (gi >= 0 && gi < H && gj >= 0 && gj < W);
        }
#pragma unroll
        for (int h2 = 0; h2 < 2; ++h2) {
            const short* bb = Bw + (n * 2 + h2) * 9 * 512;
            bf16x8 bv[9];
#pragma unroll
            for (int t = 0; t < 9; ++t) bv[t] = *(const bf16x8*)(bb + t * 512);
            bf16x8 a9[9];
#pragma unroll
            for (int rs = 0; rs < 9; ++rs) {
                const short* src =
                    ok[rs] ? abase + ((rs / 3) * W + (rs % 3)) * 64 + h2 * 32
                           : zpad;
                a9[rs] = *(const bf16x8*)src;
            }
#pragma unroll
            for (int rs = 0; rs < 9; ++rs) {
#pragma unroll
                for (int t = 0; t < 9; ++t) {
                    const int y = rs / 3 - t / 3 + 1;
                    const int x = rs % 3 - t % 3 + 1;
                    if (y >= 0 && y < 3 && x >= 0 && x < 3)
                        acc[y * 3 + x] = __builtin_amdgcn_mfma_f32_16x16x32_bf16(
                            a9[rs], bv[t], acc[y * 3 + x], 0, 0, 0);
                }
            }
        }
    }
    const int oc = wave * 16 + (lane & 15);
    const float bn = bnn[oc];
    const int mrow = (lane >> 4) * 4;
#pragma unroll
    for (int j = 0; j < 4; ++j) {
        int pix = p0 + mrow + j;
        const short* mb = maskT + (size_t)pix * 72 + (oc >> 3) * 9;
        float sacc = 0.f;
#pragma unroll
        for (int yx = 0; yx < 9; ++yx) {
            float gv = leakyf(acc[yx][j] + bn);
            sacc += gv * bf2f(mb[yx]);
        }
        agg[(size_t)pix * 64 + oc] = f2bf(leakyf(sacc));
    }
}

extern "C" void kernel_launch(void* const* d_in, const int* in_sizes, int n_in,
                              void* d_out, int out_size, void* d_ws,
                              size_t ws_size, hipStream_t stream) {
    const float* ref = (const float*)d_in[0];
    const float* w1 = (const float*)d_in[1];
    const float* b1 = (const float*)d_in[2];
    const float* w2 = (const float*)d_in[3];
    const float* b2 = (const float*)d_in[4];
    const float* w3 = (const float*)d_in[5];
    const float* b3 = (const float*)d_in[6];
    const float* w4 = (const float*)d_in[7];
    const float* b4 = (const float*)d_in[8];
    const float* wm = (const float*)d_in[9];
    const float* bm = (const float*)d_in[10];
    const float* wnn = (const float*)d_in[11];
    const float* bnn = (const float*)d_in[12];
    const float* wf = (const float*)d_in[13];
    const float* bf = (const float*)d_in[14];

    char* ws = (char*)d_ws;
    constexpr size_t O_NRT = 0;
    constexpr size_t O_S = O_NRT + (size_t)BATCH * HW * 64 * 4;
    constexpr size_t O_REFT = O_S + (size_t)BATCH * 49 * 98 * 98 * 4;
    constexpr size_t O_X1 = O_REFT + (size_t)BATCH * HW * 64 * 2;
    constexpr size_t O_X2 = O_X1 + (size_t)BATCH * HW * 64 * 2;
    constexpr size_t O_MASKT = O_X2 + (size_t)BATCH * HW * 64 * 2;
    constexpr size_t O_IDX = O_MASKT + (size_t)BATCH * HW * 72 * 2;
    constexpr size_t O_P1 = O_IDX + (size_t)BATCH * HW * 3 * 4;
    constexpr size_t O_P2 = O_P1 + (size_t)E1 * 2;
    constexpr size_t O_P3 = O_P2 + (size_t)E2 * 2;
    constexpr size_t O_P4 = O_P3 + (size_t)E3 * 2;
    constexpr size_t O_PM = O_P4 + (size_t)E4 * 2;
    constexpr size_t O_PF = O_PM + (size_t)E5 * 2;
    constexpr size_t O_B2 = O_PF + (size_t)E6 * 2;
    constexpr size_t O_ZP = O_B2 + (size_t)E7 * 2;

    float* NRT = (float*)(ws + O_NRT);
    float* S = (float*)(ws + O_S);
    short* REFT = (short*)(ws + O_REFT);
    short* X1 = (short*)(ws + O_X1);
    short* X2 = (short*)(ws + O_X2);
    short* MASKT = (short*)(ws + O_MASKT);
    int* IDX = (int*)(ws + O_IDX);
    short* P1 = (short*)(ws + O_P1);
    short* P2 = (short*)(ws + O_P2);
    short* P3 = (short*)(ws + O_P3);
    short* P4 = (short*)(ws + O_P4);
    short* PM = (short*)(ws + O_PM);
    short* PF = (short*)(ws + O_PF);
    short* B2 = (short*)(ws + O_B2);
    short* ZPAD = (short*)(ws + O_ZP);

    constexpr int CONVB = 6 * 12 * BATCH * 4;        // 1152
    constexpr int CORRB = BATCH * 49;                // 196 tile blocks
    constexpr int TOPKB = BATCH * HW / 256;          // 144
    constexpr int ZFB = (BATCH * 24 * 98 * 49 + 255) / 256;

    // input prep + single fused weight-pack kernel + S border zero-fill
    k_pre<<<(BATCH * HW + 255) / 256, 256, 0, stream>>>(ref, REFT, NRT);
    k_prep_all<<<(CT + 255) / 256, 256, 0, stream>>>(w1, w2, w3, w4, wm, wf, wnn,
                                                     P1, P2, P3, P4, PM, PF, B2,
                                                     ZPAD);
    k_zfill<<<ZFB, 256, 0, stream>>>(S);

    // fat kernel 1: conv1 (REFT->X1) || corr_tile (NRT->S)
    k_cmfma<3, 3, 64, 64, 0, true, 4, 1><<<CONVB + CORRB, 256, 0, stream>>>(
        REFT, nullptr, P1, b1, X1, NRT, S, nullptr, CONVB);
    // fat kernel 2: conv2 (X1->X2) || topk (S->IDX)
    k_cmfma<3, 3, 64, 64, 0, true, 4, 2><<<CONVB + TOPKB, 256, 0, stream>>>(
        X1, nullptr, P2, b2, X2, S, nullptr, IDX, CONVB);
    // remaining mask-branch convs
    k_cmfma<7, 1, 64, 64, 0, true, 4, 0><<<CONVB, 256, 0, stream>>>(
        X2, nullptr, P3, b3, X1, nullptr, nullptr, nullptr, CONVB);
    k_cmfma<1, 7, 64, 64, 0, true, 4, 0><<<CONVB, 256, 0, stream>>>(
        X1, nullptr, P4, b4, X2, nullptr, nullptr, nullptr, CONVB);
    k_cmfma<3, 3, 64, 72, 1, true, 5, 0><<<6 * 12 * BATCH * 5, 256, 0, stream>>>(
        X2, nullptr, PM, bm, MASKT, nullptr, nullptr, nullptr, 6 * 12 * BATCH * 5);

    // MFMA gather-conv + mask-weighted aggregate -> X1 (bf16 ch-last)
    k_agg_mfma<<<BATCH * HW / 16, 256, 0, stream>>>(REFT, IDX, B2, bnn, MASKT,
                                                    ZPAD, X1);

    // final fusion conv: concat([ref, agg]) -> NCHW fp32 out (B streamed)
    k_cmfma<3, 3, 128, 64, 2, false, 2, 0><<<6 * 12 * BATCH * 2, 256, 0, stream>>>(
        REFT, X1, PF, bf, d_out, nullptr, nullptr, nullptr, 6 * 12 * BATCH * 2);
}

// Round 19
// 180.318 us; speedup vs baseline: 1.1680x; 1.1680x over previous
//
#include <hip/hip_runtime.h>
#include <hip/hip_bf16.h>

constexpr int BATCH = 4;
constexpr int H = 96, W = 96, HW = H * W;
constexpr int NBR = 3;

using bf16x8 = __attribute__((ext_vector_type(8))) short;  // 8 bf16 in 4 VGPRs
using f32x4 = __attribute__((ext_vector_type(4))) float;

static __device__ __forceinline__ float leakyf(float x) {
    return x >= 0.f ? x : 0.1f * x;
}

static __device__ __forceinline__ short f2bf(float x) {
    __hip_bfloat16 h = __float2bfloat16(x);
    return *reinterpret_cast<short*>(&h);
}

static __device__ __forceinline__ float bf2f(short s) {
    __hip_bfloat16 h = *reinterpret_cast<__hip_bfloat16*>(&s);
    return __bfloat162float(h);
}

// ---- fused: ref NCHW fp32 -> REFT (bf16 ch-last) + NRT (normalized ch-last)
__global__ __launch_bounds__(256) void k_pre(const float* __restrict__ ref,
                                             short* __restrict__ reft,
                                             float* __restrict__ nrt) {
    int p = blockIdx.x * 256 + threadIdx.x;
    if (p >= BATCH * HW) return;
    int b = p / HW, ij = p % HW;
    const float* src = ref + b * 64 * HW + ij;
    float v[64];
    float ss = 0.f;
#pragma unroll
    for (int c = 0; c < 64; ++c) {
        v[c] = src[c * HW];
        ss += v[c] * v[c];
    }
    float inv = 1.f / fmaxf(sqrtf(ss), 1e-12f);
    short* rd = reft + (size_t)p * 64;
#pragma unroll
    for (int cc = 0; cc < 8; ++cc) {
        bf16x8 o;
#pragma unroll
        for (int j = 0; j < 8; ++j) o[j] = f2bf(v[cc * 8 + j]);
        *(bf16x8*)(rd + cc * 8) = o;
    }
    float* nd = nrt + (size_t)p * 64;
#pragma unroll
    for (int c = 0; c < 64; ++c) nd[c] = v[c] * inv;
}

// ---- conv-weight pack helper (OIHW fp32 -> MFMA-B fragments) ---------------
static __device__ __forceinline__ void packw(const float* __restrict__ src,
                                             short* __restrict__ dst, int i,
                                             int OC, int ICt, int ICsrc, int KH,
                                             int KW, int NT, int fold) {
    int e = i & 7, l = (i >> 3) & 63;
    int rest = i >> 9;
    int nt = rest % NT;
    rest /= NT;
    int ICK = ICt >> 5;
    int kk = rest % ICK;
    int tap = rest / ICK;
    int ic = kk * 32 + (l >> 4) * 8 + e;
    int oc = nt * 16 + (l & 15);
    int u = tap / KW, v = tap % KW;
    float val = 0.f;
    if (oc < OC) {
        val = src[((oc * ICsrc + ic) * KH + u) * KW + v];
        if (fold) val += src[((oc * ICsrc + 64 + ic) * KH + u) * KW + v];
    }
    dst[i] = f2bf(val);
}

// ---- ALL weight prep + S border zero-fill in ONE kernel --------------------
constexpr int E1 = 36864, E2 = 36864, E3 = 28672, E4 = 28672, E5 = 46080,
              E6 = 73728, E7 = 110592;
constexpr int C1 = E1, C2 = C1 + E2, C3 = C2 + E3, C4 = C3 + E4, C5 = C4 + E5,
              C6 = C5 + E6, C7 = C6 + E7, CT = C7 + 8;
constexpr int ZFN = BATCH * 24 * 98 * 49;  // zfill work items (2 px each)
constexpr int CTZ = CT + ZFN;
__global__ void k_prep_all(const float* __restrict__ w1,
                           const float* __restrict__ w2,
                           const float* __restrict__ w3,
                           const float* __restrict__ w4,
                           const float* __restrict__ wm,
                           const float* __restrict__ wf,
                           const float* __restrict__ wnn,
                           short* __restrict__ P1, short* __restrict__ P2,
                           short* __restrict__ P3, short* __restrict__ P4,
                           short* __restrict__ PM, short* __restrict__ PF,
                           short* __restrict__ B2, short* __restrict__ zpad,
                           float* __restrict__ S) {
    int i = blockIdx.x * 256 + threadIdx.x;
    if (i >= CTZ) return;
    if (i < C1) {
        packw(w1, P1, i, 64, 64, 128, 3, 3, 4, 1);
    } else if (i < C2) {
        packw(w2, P2, i - C1, 64, 64, 64, 3, 3, 4, 0);
    } else if (i < C3) {
        packw(w3, P3, i - C2, 64, 64, 64, 7, 1, 4, 0);
    } else if (i < C4) {
        packw(w4, P4, i - C3, 64, 64, 64, 1, 7, 4, 0);
    } else if (i < C5) {
        packw(wm, PM, i - C4, 72, 64, 64, 3, 3, 5, 0);
    } else if (i < C6) {
        packw(wf, PF, i - C5, 64, 128, 128, 3, 3, 4, 0);
    } else if (i < C7) {
        int j = i - C6;
        int e = j & 7, l = (j >> 3) & 63;
        int t = (j >> 9) % 9;
        int h2 = (j / (512 * 9)) % 2;
        int n = (j / (512 * 9 * 2)) % 3;
        int nt = j / (512 * 9 * 2 * 3);
        int oc = nt * 16 + (l & 15);
        int c = h2 * 32 + (l >> 4) * 8 + e;
        int u = t / 3, v = t % 3;
        B2[j] = f2bf(wnn[((oc * 192 + n * 64 + c) * 3 + u) * 3 + v]);
    } else if (i < CT) {
        zpad[i - C7] = 0;
    } else {
        // S border zero-fill: d>24 cells the mirror can never write
        int idx = i - CT;
        int xp = idx % 49, x0 = xp * 2, x1 = x0 + 1;
        int y = (idx / 49) % 98;
        int dd = (idx / (49 * 98)) % 24;
        int b = idx / (49 * 98 * 24);
        int d = 25 + dd;
        int dy = d / 7, dx = d % 7;
        float* row = S + ((size_t)(b * 49 + d)) * (98 * 98) + y * 98;
        int yy = y + dy - 3;
        if (yy < 0 || yy >= 98) {
            row[x0] = 0.f;
            row[x1] = 0.f;
        } else {
            if (x0 + dx - 3 < 0 || x0 + dx - 3 >= 98) row[x0] = 0.f;
            if (x1 + dx - 3 < 0 || x1 + dx - 3 >= 98) row[x1] = 0.f;
        }
    }
}

// ---- LDS-tiled correlation body: block = (batch, row-pair), acc[25]/thread -
constexpr int CORR_NCOL = 104;
constexpr int CORR_BYTES = (2 * 5 * CORR_NCOL + 2 * 2 * CORR_NCOL) * 16;  // 23296
static __device__ void corr_tile_body(const float* __restrict__ nrt,
                                      float* __restrict__ S, char* pool,
                                      int blk) {
    float4* f2s = (float4*)pool;                 // [g2][r5][NCOL]
    float4* f1s = f2s + 2 * 5 * CORR_NCOL;       // [g2][r2][NCOL]
    const int b = blk / 49;
    const int y0 = (blk % 49) * 2;
    const int tid = threadIdx.x;
    const int x = tid % 98, yloc = tid / 98;  // valid when tid < 196
    const int y = y0 + yloc;
    float acc[25];
#pragma unroll
    for (int d = 0; d < 25; ++d) acc[d] = 0.f;
    for (int c0 = 0; c0 < 64; c0 += 8) {
        for (int e = tid; e < 2 * 5 * CORR_NCOL; e += 256) {
            int sc = e % CORR_NCOL;
            int r = (e / CORR_NCOL) % 5;
            int g = e / (CORR_NCOL * 5);
            int iy = y0 - 4 + r, ix = sc - 4;
            float4 v = make_float4(0.f, 0.f, 0.f, 0.f);
            if (iy >= 0 && iy < H && ix >= 0 && ix < W)
                v = *(const float4*)(nrt + ((size_t)(b * HW) + iy * W + ix) * 64 +
                                     c0 + g * 4);
            f2s[(g * 5 + r) * CORR_NCOL + sc] = v;
        }
        for (int e = tid; e < 2 * 2 * CORR_NCOL; e += 256) {
            int sc = e % CORR_NCOL;
            int r = (e / CORR_NCOL) % 2;
            int g = e / (CORR_NCOL * 2);
            int iy = y0 - 1 + r, ix = sc - 4;
            float4 v = make_float4(0.f, 0.f, 0.f, 0.f);
            if (iy >= 0 && iy < H && ix >= 0 && ix < W)
                v = *(const float4*)(nrt + ((size_t)(b * HW) + iy * W + ix) * 64 +
                                     c0 + g * 4);
            f1s[(g * 2 + r) * CORR_NCOL + sc] = v;
        }
        __syncthreads();
        if (tid < 196) {
#pragma unroll
            for (int g = 0; g < 2; ++g) {
                float4 a = f1s[(g * 2 + yloc) * CORR_NCOL + (x + 3)];
#pragma unroll
                for (int d = 0; d < 25; ++d) {
                    const int dy = d / 7, dx = d % 7;
                    float4 q = f2s[(g * 5 + yloc + dy) * CORR_NCOL + (x + dx)];
                    acc[d] = fmaf(a.x, q.x,
                                  fmaf(a.y, q.y,
                                       fmaf(a.z, q.z, fmaf(a.w, q.w, acc[d]))));
                }
            }
        }
        __syncthreads();
    }
    if (tid < 196) {
#pragma unroll
        for (int d = 0; d < 25; ++d)
            S[((size_t)(b * 49 + d)) * (98 * 98) + y * 98 + x] = acc[d];
#pragma unroll
        for (int d = 0; d < 24; ++d) {
            const int dy = d / 7, dx = d % 7;
            int y2 = y + dy - 3, x2 = x + dx - 3;
            if (y2 >= 0 && y2 < 98 && x2 >= 0 && x2 < 98)
                S[((size_t)(b * 49 + 48 - d)) * (98 * 98) + y2 * 98 + x2] = acc[d];
        }
    }
}

// ---- topk tail body: 3x3 window-sum + top-3 (stable: strict >) -------------
static __device__ void topk_body(const float* __restrict__ S,
                                 int* __restrict__ idx3, int blk) {
    int p = blk * 256 + threadIdx.x;
    if (p >= BATCH * HW) return;
    int b = p / HW, i = (p % HW) / W, j = p % W;
    float v0 = -1e30f, v1 = -1e30f, v2 = -1e30f;
    int d0 = 0, d1 = 0, d2 = 0;
    for (int d = 0; d < 49; ++d) {
        const float* s = S + ((b * 49 + d) * 98 + i) * 98 + j;
        float v = 0.f;
#pragma unroll
        for (int u = 0; u < 3; ++u)
#pragma unroll
            for (int vv = 0; vv < 3; ++vv) v += s[u * 98 + vv];
        if (v > v0) {
            v2 = v1; d2 = d1; v1 = v0; d1 = d0; v0 = v; d0 = d;
        } else if (v > v1) {
            v2 = v1; d2 = d1; v1 = v; d1 = d;
        } else if (v > v2) {
            v2 = v; d2 = d;
        }
    }
    idx3[p * 3 + 0] = d0;
    idx3[p * 3 + 1] = d1;
    idx3[p * 3 + 2] = d2;
}

// ---- channel-last bf16 implicit-GEMM conv (fat: optional fused tail) -------
template <int KH, int KW, int IC, int OC, int OMODE, bool BLDS, int NSPL, int TAIL>
__global__ __launch_bounds__(256) void k_cmfma(
    const short* __restrict__ inA, const short* __restrict__ inB,
    const short* __restrict__ Bp, const float* __restrict__ bias,
    void* __restrict__ outp, const float* __restrict__ taux,
    float* __restrict__ tS, int* __restrict__ tidx, int convblks) {
    constexpr int TI = 8, TJ = 16;
    constexpr int PH = (KH - 1) / 2, PW = (KW - 1) / 2;
    constexpr int LR = TI + KH - 1, LC = TJ + KW - 1;
    constexpr int ICB = IC * 2;
    constexpr int LS = (ICB == 128) ? 7 : 8;
    constexpr int ICK = IC / 32;
    constexpr int NTF = (OC + 15) / 16;
    constexpr int NTb = NTF / NSPL;
    constexpr int TAPS = KH * KW;
    constexpr int NOCT = ICB / 16;
    constexpr int XS_BYTES = LR * LC * ICB;
    constexpr int BS_BYTES = BLDS ? TAPS * ICK * NTb * 1024 : 16;
    constexpr int CONV_BYTES = XS_BYTES + BS_BYTES;
    constexpr int POOL =
        (TAIL == 1 && CORR_BYTES > CONV_BYTES) ? CORR_BYTES : CONV_BYTES;
    __shared__ __align__(16) char pool[POOL];
    if (TAIL != 0 && (int)blockIdx.x >= convblks) {
        int xb = (int)blockIdx.x - convblks;
        if (TAIL == 1)
            corr_tile_body(taux, tS, pool, xb);
        else
            topk_body(taux, tidx, xb);
        return;
    }
    char* Xs = pool;
    short* Bs = (short*)(pool + XS_BYTES);
    const int lid = blockIdx.x;
    const int tj0 = (lid % 6) * TJ, ti0 = ((lid / 6) % 12) * TI;
    const int zz = lid / 72;
    const int b = zz / NSPL;
    const int nt0 = (zz % NSPL) * NTb;
    const int tid = threadIdx.x;
    if (BLDS) {
        for (int u2 = tid; u2 < TAPS * ICK * NTb * 64; u2 += 256) {
            int l2 = u2 & 63;
            int rest = u2 >> 6;
            int nt = rest % NTb;
            int qk = rest / NTb;
            ((bf16x8*)Bs)[u2] = ((const bf16x8*)Bp)[(qk * NTF + nt0 + nt) * 64 + l2];
        }
    }
    for (int u2 = tid; u2 < LR * LC * NOCT; u2 += 256) {
        int oct = u2 % NOCT;
        int hp = u2 / NOCT;
        int hr = hp / LC, hc = hp % LC;
        int gi = ti0 + hr - PH, gj = tj0 + hc - PW;
        bf16x8 v = {};
        if (gi >= 0 && gi < H && gj >= 0 && gj < W) {
            const short* s = (oct < 8) ? inA : inB;
            v = *(const bf16x8*)(s + (size_t)(b * HW + gi * W + gj) * 64 +
                                 (oct & 7) * 8);
        }
        int byte = hp * ICB + oct * 16;
        byte ^= ((byte >> LS) & 7) << 4;
        *(bf16x8*)(Xs + byte) = v;
    }
    __syncthreads();
    const int wave = tid >> 6, l = tid & 63;
    const int r = l & 15, q = l >> 4;
    const int mt0 = wave * 2;
    int p0 = mt0 * 16 + r, p1 = p0 + 16;
    int li0 = p0 >> 4, lj0 = p0 & 15, li1 = p1 >> 4, lj1 = p1 & 15;
    f32x4 acc[2][NTb] = {};
#pragma unroll
    for (int t = 0; t < TAPS; ++t) {
        const int u = t / KW, v = t % KW;
        int hp0 = (li0 + u) * LC + (lj0 + v);
        int hp1 = (li1 + u) * LC + (lj1 + v);
#pragma unroll
        for (int kk = 0; kk < ICK; ++kk) {
            int ab0 = hp0 * ICB + kk * 64 + q * 16;
            ab0 ^= ((ab0 >> LS) & 7) << 4;
            int ab1 = hp1 * ICB + kk * 64 + q * 16;
            ab1 ^= ((ab1 >> LS) & 7) << 4;
            bf16x8 a0 = *(const bf16x8*)(Xs + ab0);
            bf16x8 a1 = *(const bf16x8*)(Xs + ab1);
            const short* bbase =
                BLDS ? (const short*)Bs + (t * ICK + kk) * NTb * 512 + l * 8
                     : Bp + ((t * ICK + kk) * NTF + nt0) * 512 + l * 8;
#pragma unroll
            for (int nt = 0; nt < NTb; ++nt) {
                bf16x8 bv = *(const bf16x8*)(bbase + nt * 512);
                acc[0][nt] =
                    __builtin_amdgcn_mfma_f32_16x16x32_bf16(a0, bv, acc[0][nt], 0, 0, 0);
                acc[1][nt] =
                    __builtin_amdgcn_mfma_f32_16x16x32_bf16(a1, bv, acc[1][nt], 0, 0, 0);
            }
        }
    }
    const int col = l & 15;
#pragma unroll
    for (int mt = 0; mt < 2; ++mt)
#pragma unroll
        for (int nt = 0; nt < NTb; ++nt) {
            int oc = (nt0 + nt) * 16 + col;
            float bs = (oc < OC) ? bias[oc] : 0.f;
#pragma unroll
            for (int j = 0; j < 4; ++j) {
                int p = (mt0 + mt) * 16 + q * 4 + j;
                int gi = ti0 + (p >> 4), gj = tj0 + (p & 15);
                float val = acc[mt][nt][j] + bs;
                if (OMODE == 0) {
                    val = leakyf(val);
                    *((short*)outp + (size_t)(b * HW + gi * W + gj) * 64 + oc) =
                        f2bf(val);
                } else if (OMODE == 1) {
                    if (oc < 72)
                        *((short*)outp + (size_t)(b * HW + gi * W + gj) * 72 + oc) =
                            f2bf(val);
                } else {
                    val = leakyf(val);
                    *((float*)outp + (size_t)(b * 64 + oc) * HW + gi * W + gj) = val;
                }
            }
        }
}

// ---- MFMA gather-conv + mask reduce, single-buffer DMA (R17 measured best) -
__global__ __launch_bounds__(512, 4) void k_agg_mfma(
    const short* __restrict__ refT, const int* __restrict__ idx3,
    const short* __restrict__ B2, const float* __restrict__ bnn,
    const short* __restrict__ maskT, const short* __restrict__ zpad,
    short* __restrict__ agg) {
    constexpr int PX = 32;
    __shared__ short A_lds[2 * 18 * 64 * 8];  // 36,864 B
    __shared__ short sgi[PX][NBR], sgj[PX][NBR];
    const int bid = blockIdx.x;
    const int swz = (bid & 7) * ((int)gridDim.x >> 3) + (bid >> 3);
    const int p0 = swz * PX;
    const int b = p0 / HW;
    const int i0 = (p0 % HW) / W;
    const int j0 = p0 % W;
    const int tid = threadIdx.x;
    const int wave = tid >> 6;
    const int lane = tid & 63;
    if (tid < PX * NBR) {
        int px = tid / NBR, n = tid % NBR;
        int d = idx3[(p0 + px) * NBR + n];
        sgi[px][n] = (short)(i0 + d / 7 - 4);
        sgj[px][n] = (short)(j0 + px + d % 7 - 4);
    }
    __syncthreads();

    auto STAGE = [&](int n) {
        for (int r2 = wave; r2 < 36; r2 += 8) {
            int kkl = r2 % 18;
            int ph = r2 / 18;
            int rs = kkl >> 1;
            int oh = kkl & 1;
            int c = lane ^ (((lane >> 4) & 3) | ((r2 & 1) << 2));
            int oct = oh * 4 + (c >> 4);
            int px = ph * 16 + (c & 15);
            int gi = sgi[px][n] + rs / 3;
            int gj = sgj[px][n] + rs % 3;
            const short* src = (gi >= 0 && gi < H && gj >= 0 && gj < W)
                                   ? refT + (size_t)(b * HW + gi * W + gj) * 64 +
                                         oct * 8
                                   : zpad;
            __builtin_amdgcn_global_load_lds(
                (const __attribute__((address_space(1))) void*)src,
                (__attribute__((address_space(3))) void*)((char*)A_lds +
                                                          r2 * 1024),
                16, 0, 0);
        }
    };

    const int w = wave & 3;      // oc slice
    const int half = wave >> 2;  // pixel group
    f32x4 acc[9] = {};
    const short* Bw = B2 + (size_t)w * (3 * 2 * 9 * 512) + lane * 8;

    auto COMPUTE = [&](int n) {
#pragma unroll
        for (int h2 = 0; h2 < 2; ++h2) {
            const short* bb = Bw + (n * 2 + h2) * 9 * 512;
            bf16x8 bv[9];
#pragma unroll
            for (int t = 0; t < 9; ++t) bv[t] = *(const bf16x8*)(bb + t * 512);
#pragma unroll
            for (int rs = 0; rs < 9; ++rs) {
                int kkl = rs * 2 + h2;
                int ab = ((((half * 18 + kkl) << 6) + lane) << 4);
                ab ^= ((ab >> 8) & 7) << 4;
                bf16x8 a = *(const bf16x8*)((char*)A_lds + ab);
#pragma unroll
                for (int t = 0; t < 9; ++t) {
                    const int y = rs / 3 - t / 3 + 1;
                    const int x = rs % 3 - t % 3 + 1;
                    if (y >= 0 && y < 3 && x >= 0 && x < 3)
                        acc[y * 3 + x] = __builtin_amdgcn_mfma_f32_16x16x32_bf16(
                            a, bv[t], acc[y * 3 + x], 0, 0, 0);
                }
            }
        }
    };

    STAGE(0);
    __syncthreads();
    COMPUTE(0);
    __syncthreads();
    STAGE(1);
    __syncthreads();
    COMPUTE(1);
    __syncthreads();
    STAGE(2);
    __syncthreads();
    COMPUTE(2);

    const int oc = w * 16 + (lane & 15);
    const float bn = bnn[oc];
    const int mrow = (lane >> 4) * 4;
#pragma unroll
    for (int j = 0; j < 4; ++j) {
        int px = half * 16 + mrow + j;
        int ij = i0 * W + j0 + px;
        const short* mb = maskT + (size_t)(b * HW + ij) * 72 + (oc >> 3) * 9;
        float sacc = 0.f;
#pragma unroll
        for (int yx = 0; yx < 9; ++yx) {
            float gv = leakyf(acc[yx][j] + bn);
            sacc += gv * bf2f(mb[yx]);
        }
        agg[(size_t)(b * HW + ij) * 64 + oc] = f2bf(leakyf(sacc));
    }
}

extern "C" void kernel_launch(void* const* d_in, const int* in_sizes, int n_in,
                              void* d_out, int out_size, void* d_ws,
                              size_t ws_size, hipStream_t stream) {
    const float* ref = (const float*)d_in[0];
    const float* w1 = (const float*)d_in[1];
    const float* b1 = (const float*)d_in[2];
    const float* w2 = (const float*)d_in[3];
    const float* b2 = (const float*)d_in[4];
    const float* w3 = (const float*)d_in[5];
    const float* b3 = (const float*)d_in[6];
    const float* w4 = (const float*)d_in[7];
    const float* b4 = (const float*)d_in[8];
    const float* wm = (const float*)d_in[9];
    const float* bm = (const float*)d_in[10];
    const float* wnn = (const float*)d_in[11];
    const float* bnn = (const float*)d_in[12];
    const float* wf = (const float*)d_in[13];
    const float* bf = (const float*)d_in[14];

    char* ws = (char*)d_ws;
    constexpr size_t O_NRT = 0;
    constexpr size_t O_S = O_NRT + (size_t)BATCH * HW * 64 * 4;
    constexpr size_t O_REFT = O_S + (size_t)BATCH * 49 * 98 * 98 * 4;
    constexpr size_t O_X1 = O_REFT + (size_t)BATCH * HW * 64 * 2;
    constexpr size_t O_X2 = O_X1 + (size_t)BATCH * HW * 64 * 2;
    constexpr size_t O_MASKT = O_X2 + (size_t)BATCH * HW * 64 * 2;
    constexpr size_t O_IDX = O_MASKT + (size_t)BATCH * HW * 72 * 2;
    constexpr size_t O_P1 = O_IDX + (size_t)BATCH * HW * 3 * 4;
    constexpr size_t O_P2 = O_P1 + (size_t)E1 * 2;
    constexpr size_t O_P3 = O_P2 + (size_t)E2 * 2;
    constexpr size_t O_P4 = O_P3 + (size_t)E3 * 2;
    constexpr size_t O_PM = O_P4 + (size_t)E4 * 2;
    constexpr size_t O_PF = O_PM + (size_t)E5 * 2;
    constexpr size_t O_B2 = O_PF + (size_t)E6 * 2;
    constexpr size_t O_ZP = O_B2 + (size_t)E7 * 2;

    float* NRT = (float*)(ws + O_NRT);
    float* S = (float*)(ws + O_S);
    short* REFT = (short*)(ws + O_REFT);
    short* X1 = (short*)(ws + O_X1);
    short* X2 = (short*)(ws + O_X2);
    short* MASKT = (short*)(ws + O_MASKT);
    int* IDX = (int*)(ws + O_IDX);
    short* P1 = (short*)(ws + O_P1);
    short* P2 = (short*)(ws + O_P2);
    short* P3 = (short*)(ws + O_P3);
    short* P4 = (short*)(ws + O_P4);
    short* PM = (short*)(ws + O_PM);
    short* PF = (short*)(ws + O_PF);
    short* B2 = (short*)(ws + O_B2);
    short* ZPAD = (short*)(ws + O_ZP);

    constexpr int CONVB = 6 * 12 * BATCH * 4;        // 1152
    constexpr int CORRB = BATCH * 49;                // 196 tile blocks
    constexpr int TOPKB = BATCH * HW / 256;          // 144

    // input prep + fused weight-pack/zfill kernel
    k_pre<<<(BATCH * HW + 255) / 256, 256, 0, stream>>>(ref, REFT, NRT);
    k_prep_all<<<(CTZ + 255) / 256, 256, 0, stream>>>(w1, w2, w3, w4, wm, wf,
                                                      wnn, P1, P2, P3, P4, PM,
                                                      PF, B2, ZPAD, S);

    // fat kernel 1: conv1 (REFT->X1) || corr_tile (NRT->S)
    k_cmfma<3, 3, 64, 64, 0, true, 4, 1><<<CONVB + CORRB, 256, 0, stream>>>(
        REFT, nullptr, P1, b1, X1, NRT, S, nullptr, CONVB);
    // fat kernel 2: conv2 (X1->X2) || topk (S->IDX)
    k_cmfma<3, 3, 64, 64, 0, true, 4, 2><<<CONVB + TOPKB, 256, 0, stream>>>(
        X1, nullptr, P2, b2, X2, S, nullptr, IDX, CONVB);
    // remaining mask-branch convs
    k_cmfma<7, 1, 64, 64, 0, true, 4, 0><<<CONVB, 256, 0, stream>>>(
        X2, nullptr, P3, b3, X1, nullptr, nullptr, nullptr, CONVB);
    k_cmfma<1, 7, 64, 64, 0, true, 4, 0><<<CONVB, 256, 0, stream>>>(
        X1, nullptr, P4, b4, X2, nullptr, nullptr, nullptr, CONVB);
    k_cmfma<3, 3, 64, 72, 1, true, 5, 0><<<6 * 12 * BATCH * 5, 256, 0, stream>>>(
        X2, nullptr, PM, bm, MASKT, nullptr, nullptr, nullptr, 6 * 12 * BATCH * 5);

    // MFMA gather-conv + mask-weighted aggregate -> X1 (bf16 ch-last)
    k_agg_mfma<<<BATCH * HW / 32, 512, 0, stream>>>(REFT, IDX, B2, bnn, MASKT,
                                                    ZPAD, X1);

    // final fusion conv: concat([ref, agg]) -> NCHW fp32 out (B streamed)
    k_cmfma<3, 3, 128, 64, 2, false, 2, 0><<<6 * 12 * BATCH * 2, 256, 0, stream>>>(
        REFT, X1, PF, bf, d_out, nullptr, nullptr, nullptr, 6 * 12 * BATCH * 2);
}